// Round 7
// baseline (312.795 us; speedup 1.0000x reference)
//
#include <hip/hip_runtime.h>
#include <hip/hip_bf16.h>
#include <cstddef>
#include <cstdint>

#define T_DIM 4096
#define B_DIM 8
#define N_DIM 256
#define H_DIM 512
#define NT_DIM 5

typedef __attribute__((ext_vector_type(8))) short short8;
typedef __attribute__((ext_vector_type(4))) float f32x4;

__device__ __forceinline__ short cvt_bf16(float f) {
  __hip_bfloat16 h = __float2bfloat16(f);
  union { __hip_bfloat16 h; short s; } u; u.h = h; return u.s;
}

// async global->LDS, 16B/lane; LDS dest = wave-uniform base + lane*16
typedef __attribute__((address_space(1))) const void gvoid_t;
typedef __attribute__((address_space(3))) void lvoid_t;
__device__ __forceinline__ void gl_lds16(const void* g, void* lds_wave_base) {
  __builtin_amdgcn_global_load_lds((gvoid_t*)(uintptr_t)g,
                                   (lvoid_t*)(uint32_t)(uintptr_t)lds_wave_base,
                                   16, 0, 0);
}

#define MFMA16(a, b, c) __builtin_amdgcn_mfma_f32_16x16x32_bf16(a, b, c, 0, 0, 0)

// dual-domain pointer set: dom = blockIdx.z >> zlog, zz = blockIdx.z & mask
struct GP {
  const void* A[2];
  const short* B[2];
  void* C[2];
  const float* R[2];
};

// ---------------------------------------------------------------------------
// TN GEMM: C[m,n] = scale * sum_k A[m,k] * Bt[n,k]  (+ Res[m,n])
// 128x128 tile, 4 waves, BK=32.  bf16 A/B: global_load_lds, 3-deep counted
// vmcnt pipeline (vmcnt(8) steady).  f32 A: 2-deep reg-prefetch (proven r5).
// Epilogue: per-wave LDS restage -> coalesced dwordx4 IO, Res pipelined.
// ---------------------------------------------------------------------------
template<typename TA, typename TC, bool ADD_RES>
__global__ __launch_bounds__(256)
void gemm_tn(GP p, int zlog, long long a_bs, int lda,
             long long b_bs, int ldb, long long c_bs, int ldc,
             int K, float scale) {
  constexpr bool F32A = (sizeof(TA) == 4);
  constexpr int ASTR = F32A ? 40 : 32;
  constexpr int AB = 128 * ASTR * 2;
  constexpr int BB = 128 * 32 * 2;
  constexpr int HALF = AB + BB;
  constexpr int NBUF = F32A ? 2 : 3;
  constexpr int EPIB = 4 * 16 * 68 * 4;
  constexpr int SMEMB = (NBUF * HALF) > EPIB ? (NBUF * HALF) : EPIB;
  __shared__ __align__(16) char smem[SMEMB];

  const int tid  = threadIdx.x;
  const int lane = tid & 63;
  const int wave = tid >> 6;
  const int wr   = (wave >> 1) * 64;
  const int wc   = (wave & 1) * 64;
  const int lrow = lane & 15;
  const int kgrp = lane >> 4;

  const int dom = blockIdx.z >> zlog;
  const long long zz = blockIdx.z & ((1u << zlog) - 1u);

  const TA*    Abase = (const TA*)p.A[dom] + zz * a_bs + (long long)(blockIdx.x * 128) * lda;
  const short* Bbase = p.B[dom] + zz * b_bs + (long long)(blockIdx.y * 128) * ldb;

  const int ch_r  = lane >> 2;
  const int swcol = ((lane & 3) ^ (ch_r & 3)) * 8;
  const int srow = tid >> 1;
  const int scol = (tid & 1) * 16;

  f32x4 acc[4][4] = {};
  f32x4 pv[4];

  auto stageA_bf16 = [&](int bufoff, int k0) {
    short* As = (short*)(smem + bufoff);
    #pragma unroll
    for (int i = 0; i < 2; ++i) {
      const int c = wave + 4 * i;
      gl_lds16((const short*)Abase + (long long)(c * 16 + ch_r) * lda + k0 + swcol,
               &As[c * 512]);
    }
  };
  auto stageB = [&](int bufoff, int k0) {
    short* Bs = (short*)(smem + bufoff + AB);
    #pragma unroll
    for (int i = 0; i < 2; ++i) {
      const int c = wave + 4 * i;
      gl_lds16(Bbase + (long long)(c * 16 + ch_r) * ldb + k0 + swcol, &Bs[c * 512]);
    }
  };
  auto loadA_f32 = [&](int k0) {
    const float* gp = (const float*)Abase + (long long)srow * lda + k0 + scol;
    pv[0] = *(const f32x4*)(gp + 0);
    pv[1] = *(const f32x4*)(gp + 4);
    pv[2] = *(const f32x4*)(gp + 8);
    pv[3] = *(const f32x4*)(gp + 12);
  };
  auto writeA_f32 = [&](int bufoff) {
    short* As = (short*)(smem + bufoff);
    short8 s0, s1;
    #pragma unroll
    for (int e = 0; e < 4; ++e) {
      s0[e]     = cvt_bf16(pv[0][e]);
      s0[4 + e] = cvt_bf16(pv[1][e]);
      s1[e]     = cvt_bf16(pv[2][e]);
      s1[4 + e] = cvt_bf16(pv[3][e]);
    }
    *(short8*)&As[srow * ASTR + scol]     = s0;
    *(short8*)&As[srow * ASTR + scol + 8] = s1;
  };
  auto compute = [&](int bufoff) {
    short* As = (short*)(smem + bufoff);
    short* Bs = (short*)(smem + bufoff + AB);
    short8 af[4], bfr[4];
    const int u = kgrp ^ (lrow & 3);
    #pragma unroll
    for (int i = 0; i < 4; ++i) {
      const int row = wr + i * 16 + lrow;
      if constexpr (F32A) af[i] = *(const short8*)&As[row * ASTR + kgrp * 8];
      else                af[i] = *(const short8*)&As[row * 32 + u * 8];
    }
    #pragma unroll
    for (int j = 0; j < 4; ++j) {
      const int row = wc + j * 16 + lrow;
      bfr[j] = *(const short8*)&Bs[row * 32 + u * 8];
    }
    #pragma unroll
    for (int i = 0; i < 4; ++i)
      #pragma unroll
      for (int j = 0; j < 4; ++j)
        acc[i][j] = MFMA16(af[i], bfr[j], acc[i][j]);
  };

  const int NT = K >> 5;
  if constexpr (F32A) {
    loadA_f32(0); writeA_f32(0); stageB(0, 0);
    __syncthreads();
    int cur = 0;
    for (int t = 0; t < NT; ++t) {
      const int nxt = (cur ^ 1) * HALF;
      const bool more = (t + 1 < NT);
      if (more) { loadA_f32((t + 1) << 5); stageB(nxt, (t + 1) << 5); }
      compute(cur * HALF);
      if (more) writeA_f32(nxt);
      __syncthreads();
      cur ^= 1;
    }
  } else {
    // 3-deep counted-vmcnt pipeline
    stageA_bf16(0, 0); stageB(0, 0);
    stageA_bf16(HALF, 32); stageB(HALF, 32);
    for (int t = 0; t < NT; ++t) {
      const int cb_ = (t % 3) * HALF;
      __builtin_amdgcn_s_barrier();           // compute of buffer being refilled done
      if (t + 2 < NT) {
        const int nb_ = ((t + 2) % 3) * HALF;
        stageA_bf16(nb_, (t + 2) << 5); stageB(nb_, (t + 2) << 5);
        __builtin_amdgcn_sched_barrier(0);
        asm volatile("s_waitcnt vmcnt(8)" ::: "memory");
      } else if (t + 1 < NT) {
        asm volatile("s_waitcnt vmcnt(4)" ::: "memory");
      } else {
        asm volatile("s_waitcnt vmcnt(0)" ::: "memory");
      }
      __builtin_amdgcn_sched_barrier(0);
      __builtin_amdgcn_s_barrier();           // cb_ staged for ALL waves
      __builtin_amdgcn_sched_barrier(0);
      compute(cb_);
    }
  }

  // ---- epilogue ----
  __syncthreads();
  float* myEp = (float*)smem + wave * (16 * 68);
  TC* Cd = (TC*)p.C[dom];
  const float* Res = p.R[dom];
  const long long cb = zz * c_bs;
  const int gm = blockIdx.x * 128 + wr;
  const int gn = blockIdx.y * 128 + wc;
  const int er = lane >> 2;
  const int ec = (lane & 3) * 16;

  f32x4 resA[4], resB[4];
  if constexpr (ADD_RES) {
    const long long b0 = cb + (long long)(gm + er) * ldc + gn + ec;
    #pragma unroll
    for (int q = 0; q < 4; ++q) resA[q] = *(const f32x4*)&Res[b0 + q * 4];
  }

  #pragma unroll
  for (int i = 0; i < 4; ++i) {
    if constexpr (ADD_RES) {
      if (i < 3) {
        const long long bn = cb + (long long)(gm + (i + 1) * 16 + er) * ldc + gn + ec;
        #pragma unroll
        for (int q = 0; q < 4; ++q) resB[q] = *(const f32x4*)&Res[bn + q * 4];
      }
    }
    #pragma unroll
    for (int j = 0; j < 4; ++j)
      #pragma unroll
      for (int r = 0; r < 4; ++r)
        myEp[(kgrp * 4 + r) * 68 + j * 16 + lrow] = acc[i][j][r];
    float vals[16];
    #pragma unroll
    for (int q = 0; q < 4; ++q) {
      f32x4 t4 = *(const f32x4*)&myEp[er * 68 + ec + q * 4];
      vals[q * 4 + 0] = t4[0]; vals[q * 4 + 1] = t4[1];
      vals[q * 4 + 2] = t4[2]; vals[q * 4 + 3] = t4[3];
    }
    const int row_g = gm + i * 16 + er;
    const long long base = cb + (long long)row_g * ldc + gn + ec;
    if constexpr (sizeof(TC) == 2) {
      short8 s0, s1;
      #pragma unroll
      for (int e = 0; e < 8; ++e) {
        s0[e] = cvt_bf16(vals[e] * scale);
        s1[e] = cvt_bf16(vals[8 + e] * scale);
      }
      *(short8*)&Cd[base]     = s0;
      *(short8*)&Cd[base + 8] = s1;
    } else {
      #pragma unroll
      for (int q = 0; q < 4; ++q) {
        f32x4 o;
        #pragma unroll
        for (int e = 0; e < 4; ++e) o[e] = vals[q * 4 + e] * scale;
        if constexpr (ADD_RES) {
          #pragma unroll
          for (int e = 0; e < 4; ++e) o[e] += resA[q][e];
        }
        *(f32x4*)&Cd[base + q * 4] = o;
      }
    }
    if constexpr (ADD_RES) {
      #pragma unroll
      for (int q = 0; q < 4; ++q) resA[q] = resB[q];
    }
  }
}

// ---------------------------------------------------------------------------
// FUSED logits + combine + masked softmax + attn(bf16) + nomask-transpose.
// Grid (T/128, B); 512 thr = 8 waves (2m x 4n); BM=128, BN=256(all N), K=512.
// Both domains computed in-block; 3-deep staged K/Q tiles (48 chunks/tile,
// 6 gl_lds per wave, vmcnt(12) steady).
// ---------------------------------------------------------------------------
__global__ __launch_bounds__(512)
void logits_softmax_fused(const short* __restrict__ Qvg, const short* __restrict__ Qtg,
                          const short* __restrict__ KVv, const short* __restrict__ KVt,
                          const int* __restrict__ vmask, const int* __restrict__ tmask,
                          const float* __restrict__ vaw, const float* __restrict__ taw,
                          short* __restrict__ Avg, short* __restrict__ Atg,
                          float* __restrict__ Onm_v, float* __restrict__ Onm_t) {
  constexpr int TILEB = 48 * 1024;
  __shared__ __align__(16) char smem[3 * TILEB];   // 144 KB
  __shared__ float rowstat[128][4];

  const int tid  = threadIdx.x;
  const int lane = tid & 63;
  const int wave = tid >> 6;   // 0..7
  const int wm   = wave >> 2;  // 0..1
  const int wn   = wave & 3;   // 0..3
  const int lrow = lane & 15;
  const int kgrp = lane >> 4;
  const int b    = blockIdx.y;
  const int t0   = blockIdx.x * 128;

  const float sv = 1.f / (1.f + __expf(-vaw[0]));
  const float st = 1.f / (1.f + __expf(-taw[0]));
  const float rsq = 0.044194173824159216f;   // 1/sqrt(512)

  int mkv[4], mkt[4];
  #pragma unroll
  for (int j = 0; j < 4; ++j) {
    const int n = wn * 64 + j * 16 + lrow;
    mkv[j] = vmask[b * 256 + n];
    mkt[j] = tmask[b * 256 + n];
  }

  // staging: 48 chunks (1 KiB = 16 rows x 32 shorts each); 6 per wave
  const int ch_r = lane >> 2;
  const int sw8  = ((lane & 3) ^ (ch_r & 3)) * 8;
  const short* gsrc[6];
  int loff[6];
  #pragma unroll
  for (int i = 0; i < 6; ++i) {
    const int c = wave * 6 + i;
    const short* s;
    if (c < 8)       s = Qvg + (long long)(t0 + c * 16 + ch_r) * 4096 + b * 512;
    else if (c < 16) s = Qtg + (long long)(t0 + (c - 8) * 16 + ch_r) * 4096 + b * 512;
    else if (c < 32) s = KVv + (long long)((c - 16) * 16 + ch_r) * 8192 + b * 1024;
    else             s = KVt + (long long)((c - 32) * 16 + ch_r) * 8192 + b * 1024;
    gsrc[i] = s + sw8;
    loff[i] = c * 1024;
  }
  auto stage = [&](int buf, int k0) {
    #pragma unroll
    for (int i = 0; i < 6; ++i)
      gl_lds16(gsrc[i] + k0, smem + buf * TILEB + loff[i]);
  };

  f32x4 accv[4][4] = {}, acct[4][4] = {};

  auto compute = [&](int buf) {
    const short* L = (const short*)(smem + buf * TILEB);
    const int u = kgrp ^ (lrow & 3);
    short8 qv[4], qt[4], kv[4], kt[4];
    #pragma unroll
    for (int i = 0; i < 4; ++i) {
      const int r = wm * 64 + i * 16 + lrow;
      qv[i] = *(const short8*)&L[r * 32 + u * 8];
      qt[i] = *(const short8*)&L[4096 + r * 32 + u * 8];
    }
    #pragma unroll
    for (int j = 0; j < 4; ++j) {
      const int r = wn * 64 + j * 16 + lrow;
      kv[j] = *(const short8*)&L[8192 + r * 32 + u * 8];
      kt[j] = *(const short8*)&L[16384 + r * 32 + u * 8];
    }
    #pragma unroll
    for (int i = 0; i < 4; ++i)
      #pragma unroll
      for (int j = 0; j < 4; ++j) {
        accv[i][j] = MFMA16(qv[i], kv[j], accv[i][j]);
        acct[i][j] = MFMA16(qt[i], kt[j], acct[i][j]);
      }
  };

  stage(0, 0); stage(1, 32);
  #pragma unroll 1
  for (int t = 0; t < 16; ++t) {
    __builtin_amdgcn_s_barrier();
    if (t + 2 < 16) {
      stage((t + 2) % 3, (t + 2) * 32);
      __builtin_amdgcn_sched_barrier(0);
      asm volatile("s_waitcnt vmcnt(12)" ::: "memory");
    } else if (t + 1 < 16) {
      asm volatile("s_waitcnt vmcnt(6)" ::: "memory");
    } else {
      asm volatile("s_waitcnt vmcnt(0)" ::: "memory");
    }
    __builtin_amdgcn_sched_barrier(0);
    __builtin_amdgcn_s_barrier();
    __builtin_amdgcn_sched_barrier(0);
    compute(t % 3);
  }
  __syncthreads();

  // combine in f32 (in place): v = rsq*(Sv + sv*St), t = rsq*(St + st*Sv)
  #pragma unroll
  for (int i = 0; i < 4; ++i)
    #pragma unroll
    for (int j = 0; j < 4; ++j) {
      f32x4 a = accv[i][j], c = acct[i][j];
      #pragma unroll
      for (int e = 0; e < 4; ++e) {
        accv[i][j][e] = rsq * (a[e] + sv * c[e]);
        acct[i][j][e] = rsq * (c[e] + st * a[e]);
      }
    }

#define DOM_OUT(ACC, MK, AV_G, ONM_G) do {                                          \
    float lm[4][4];                                                                 \
    _Pragma("unroll") for (int i = 0; i < 4; ++i)                                   \
    _Pragma("unroll") for (int r = 0; r < 4; ++r) {                                 \
      float m = -3.4e38f;                                                           \
      _Pragma("unroll") for (int j = 0; j < 4; ++j)                                 \
        if (MK[j] > 0) m = fmaxf(m, ACC[i][j][r]);                                  \
      m = fmaxf(m, __shfl_xor(m, 1)); m = fmaxf(m, __shfl_xor(m, 2));               \
      m = fmaxf(m, __shfl_xor(m, 4)); m = fmaxf(m, __shfl_xor(m, 8));               \
      lm[i][r] = m;                                                                 \
    }                                                                               \
    if (lrow == 0) {                                                                \
      _Pragma("unroll") for (int i = 0; i < 4; ++i)                                 \
      _Pragma("unroll") for (int r = 0; r < 4; ++r)                                 \
        rowstat[wm * 64 + i * 16 + kgrp * 4 + r][wn] = lm[i][r];                    \
    }                                                                               \
    __syncthreads();                                                                \
    _Pragma("unroll") for (int i = 0; i < 4; ++i)                                   \
    _Pragma("unroll") for (int r = 0; r < 4; ++r) {                                 \
      f32x4 s = *(const f32x4*)&rowstat[wm * 64 + i * 16 + kgrp * 4 + r][0];        \
      lm[i][r] = fmaxf(fmaxf(s[0], s[1]), fmaxf(s[2], s[3]));                       \
    }                                                                               \
    __syncthreads();                                                                \
    float ls[4][4];                                                                 \
    _Pragma("unroll") for (int i = 0; i < 4; ++i)                                   \
    _Pragma("unroll") for (int r = 0; r < 4; ++r) {                                 \
      float s = 0.f;                                                                \
      _Pragma("unroll") for (int j = 0; j < 4; ++j)                                 \
        if (MK[j] > 0) s += __expf(ACC[i][j][r] - lm[i][r]);                        \
      s += __shfl_xor(s, 1); s += __shfl_xor(s, 2);                                 \
      s += __shfl_xor(s, 4); s += __shfl_xor(s, 8);                                 \
      ls[i][r] = s;                                                                 \
    }                                                                               \
    if (lrow == 0) {                                                                \
      _Pragma("unroll") for (int i = 0; i < 4; ++i)                                 \
      _Pragma("unroll") for (int r = 0; r < 4; ++r)                                 \
        rowstat[wm * 64 + i * 16 + kgrp * 4 + r][wn] = ls[i][r];                    \
    }                                                                               \
    __syncthreads();                                                                \
    _Pragma("unroll") for (int i = 0; i < 4; ++i)                                   \
    _Pragma("unroll") for (int r = 0; r < 4; ++r) {                                 \
      f32x4 s = *(const f32x4*)&rowstat[wm * 64 + i * 16 + kgrp * 4 + r][0];        \
      ls[i][r] = 1.f / (s[0] + s[1] + s[2] + s[3]);                                 \
    }                                                                               \
    __syncthreads();                                                                \
    { /* attn restage: LDS [128][264] bf16 -> coalesced short8 */                   \
      short* AL = (short*)smem;                                                     \
      _Pragma("unroll") for (int i = 0; i < 4; ++i)                                 \
      _Pragma("unroll") for (int j = 0; j < 4; ++j)                                 \
      _Pragma("unroll") for (int r = 0; r < 4; ++r) {                               \
        float e = (MK[j] > 0) ? __expf(ACC[i][j][r] - lm[i][r]) * ls[i][r] : 0.f;   \
        AL[(wm * 64 + i * 16 + kgrp * 4 + r) * 264 + wn * 64 + j * 16 + lrow] =     \
            cvt_bf16(e);                                                            \
      }                                                                             \
      __syncthreads();                                                              \
      const int rr = tid >> 2, cb0 = (tid & 3) * 64;                                \
      short* dst = AV_G + ((long long)b * T_DIM + t0 + rr) * 256 + cb0;             \
      _Pragma("unroll") for (int q = 0; q < 8; ++q)                                 \
        *(short8*)&dst[q * 8] = *(const short8*)&AL[rr * 264 + cb0 + q * 8];        \
      __syncthreads();                                                              \
    }                                                                               \
    { /* nomask transpose: LDS [256][132] f32 -> coalesced dwordx4 */               \
      float* OL = (float*)smem;                                                     \
      _Pragma("unroll") for (int i = 0; i < 4; ++i)                                 \
      _Pragma("unroll") for (int j = 0; j < 4; ++j)                                 \
      _Pragma("unroll") for (int r = 0; r < 4; ++r)                                 \
        OL[(wn * 64 + j * 16 + lrow) * 132 + wm * 64 + i * 16 + kgrp * 4 + r] =     \
            ACC[i][j][r];                                                           \
      __syncthreads();                                                              \
      const int nn = tid >> 1, c0 = (tid & 1) * 64;                                 \
      float* dst = ONM_G + ((long long)b * 256 + nn) * T_DIM + t0 + c0;             \
      _Pragma("unroll") for (int q = 0; q < 16; ++q)                                \
        *(f32x4*)&dst[q * 4] = *(const f32x4*)&OL[nn * 132 + c0 + q * 4];           \
      __syncthreads();                                                              \
    }                                                                               \
  } while (0)

  DOM_OUT(accv, mkv, Avg, Onm_v);
  DOM_OUT(acct, mkt, Atg, Onm_t);
#undef DOM_OUT
}

// ---------------------------------------------------------------------------
// Weight transpose + cvt: WT[w][n][k] = bf16(W[w][k][n]), 8 matrices 512x512
// ---------------------------------------------------------------------------
struct WSrc { const float* p[8]; };

__global__ __launch_bounds__(256)
void wtrans_kernel(WSrc s, short* __restrict__ dst) {
  __shared__ float tile[32][33];
  const int w = blockIdx.z;
  const float* src = s.p[w];
  short* d = dst + (long long)w * H_DIM * H_DIM;
  const int tx = threadIdx.x, ty = threadIdx.y;
  const int n0 = blockIdx.x * 32, k0 = blockIdx.y * 32;
  #pragma unroll
  for (int i = 0; i < 4; ++i)
    tile[ty + 8 * i][tx] = src[(long long)(k0 + ty + 8 * i) * H_DIM + n0 + tx];
  __syncthreads();
  #pragma unroll
  for (int i = 0; i < 4; ++i)
    d[(long long)(n0 + ty + 8 * i) * H_DIM + k0 + tx] = cvt_bf16(tile[tx][ty + 8 * i]);
}

// ---------------------------------------------------------------------------
// Task heads
// ---------------------------------------------------------------------------
__global__ __launch_bounds__(1024)
void task_kernel(const float* __restrict__ vtask, const float* __restrict__ ttask,
                 const float* __restrict__ vtw, const float* __restrict__ vtb,
                 const float* __restrict__ ttw, const float* __restrict__ ttb,
                 float* __restrict__ out_v, float* __restrict__ out_t) {
  const int wave = threadIdx.x >> 6;
  const int lane = threadIdx.x & 63;
  const int dom = wave >> 3;
  const int b   = wave & 7;
  const float* task = dom ? ttask : vtask;
  const float* tw   = dom ? ttw : vtw;
  const float  tb   = (dom ? ttb : vtb)[0];
  float* o = dom ? out_t : out_v;
  for (int k = 0; k < NT_DIM; ++k) {
    const float* row = task + ((long long)k * B_DIM + b) * H_DIM;
    float s = 0.f;
    for (int c = lane; c < H_DIM; c += 64) s += row[c] * tw[c];
    #pragma unroll
    for (int d = 32; d > 0; d >>= 1) s += __shfl_xor(s, d);
    if (lane == 0) o[k * B_DIM + b] = s + tb;
  }
}

// ---------------------------------------------------------------------------
extern "C" void kernel_launch(void* const* d_in, const int* in_sizes, int n_in,
                              void* d_out, int out_size, void* d_ws, size_t ws_size,
                              hipStream_t stream) {
  const float* v_action = (const float*)d_in[0];
  const float* v_frame  = (const float*)d_in[1];
  const float* v_task   = (const float*)d_in[2];
  const int*   v_mask   = (const int*)d_in[3];
  const float* t_action = (const float*)d_in[4];
  const float* t_frame  = (const float*)d_in[5];
  const float* t_task   = (const float*)d_in[6];
  const int*   t_mask   = (const int*)d_in[7];
  const float* v_aw = (const float*)d_in[16];
  const float* t_aw = (const float*)d_in[17];
  const float* v_tw = (const float*)d_in[18];
  const float* v_tb = (const float*)d_in[19];
  const float* t_tw = (const float*)d_in[20];
  const float* t_tb = (const float*)d_in[21];

  const long long TBH = (long long)T_DIM * B_DIM * H_DIM;
  const long long BTN = (long long)B_DIM * T_DIM * N_DIM;
  const long long NBH = (long long)N_DIM * B_DIM * H_DIM;
  const long long WS  = (long long)H_DIM * H_DIM;

  float* out = (float*)d_out;
  float* out_v   = out;
  float* out_t   = out + TBH;
  float* out_vnm = out + 2 * TBH;
  float* out_tnm = out + 2 * TBH + BTN;
  float* out_vta = out + 2 * TBH + 2 * BTN;
  float* out_tta = out_vta + NT_DIM * B_DIM;

  char* w = (char*)d_ws;
  auto alloc = [&](long long bytes) {
    char* p = w; w += (bytes + 255) & ~255LL; return p;
  };
  short* WT   = (short*)alloc(8 * WS * 2);
  short* Qv   = (short*)alloc(TBH * 2);
  short* Qt   = (short*)alloc(TBH * 2);
  short* KVv  = (short*)alloc(2048LL * 1024 * 2);
  short* KVt  = (short*)alloc(2048LL * 1024 * 2);
  short* VWTv = (short*)alloc(NBH * 2);    // (V@Wo)^T per b: [b][h][n]
  short* VWTt = (short*)alloc(NBH * 2);
  short* Av   = (short*)alloc(BTN * 2);
  short* At   = (short*)alloc(BTN * 2);

  // 1. weight transpose + cvt
  WSrc ws8;
  for (int i = 0; i < 8; ++i) ws8.p[i] = (const float*)d_in[8 + i];
  wtrans_kernel<<<dim3(16, 16, 8), dim3(32, 8), 0, stream>>>(ws8, WT);

  // 2. Q projections (f32 A), both domains
  {
    GP p = {{v_frame, t_frame}, {WT + 0 * WS, WT + 4 * WS}, {Qv, Qt}, {nullptr, nullptr}};
    gemm_tn<float, short, false><<<dim3(256, 4, 2), dim3(256), 0, stream>>>(
        p, 0, 0LL, H_DIM, 0LL, H_DIM, 0LL, H_DIM, 512, 1.f);
  }

  // 3. merged K|V projections, both domains
  {
    GP p = {{v_action, t_action}, {WT + 1 * WS, WT + 5 * WS}, {KVv, KVt}, {nullptr, nullptr}};
    gemm_tn<float, short, false><<<dim3(16, 8, 2), dim3(256), 0, stream>>>(
        p, 0, 0LL, H_DIM, 0LL, H_DIM, 0LL, 1024, 512, 1.f);
  }

  // 4. VWT[b][h][n] = (V@Wo)^T
  {
    GP p = {{WT + 3 * WS, WT + 7 * WS}, {KVv + 512, KVt + 512}, {VWTv, VWTt},
            {nullptr, nullptr}};
    gemm_tn<short, short, false><<<dim3(4, 2, 16), dim3(256), 0, stream>>>(
        p, 3, 0LL, H_DIM, 1024LL, 8192, (long long)H_DIM * N_DIM, N_DIM, 512, 1.f);
  }

  // 5. FUSED logits + combine + softmax + attn + nomask outputs
  logits_softmax_fused<<<dim3(T_DIM / 128, B_DIM), dim3(512), 0, stream>>>(
      Qv, Qt, KVv, KVt, v_mask, t_mask, v_aw, t_aw, Av, At, out_vnm, out_tnm);

  // 6. out = attn @ VW + frame  (K=256)
  {
    GP p = {{Av, At}, {VWTv, VWTt}, {out_v, out_t}, {v_frame, t_frame}};
    gemm_tn<short, float, true><<<dim3(32, 4, 16), dim3(256), 0, stream>>>(
        p, 3, (long long)T_DIM * N_DIM, N_DIM, (long long)H_DIM * N_DIM, N_DIM,
        512LL, B_DIM * H_DIM, 256, 1.f);
  }

  // 7. task heads
  task_kernel<<<dim3(1), dim3(1024), 0, stream>>>(
      v_task, t_task, v_tw, v_tb, t_tw, t_tb, out_vta, out_tta);
}

// Round 8
// 290.264 us; speedup vs baseline: 1.0776x; 1.0776x over previous
//
#include <hip/hip_runtime.h>
#include <hip/hip_bf16.h>
#include <cstddef>
#include <cstdint>

#define T_DIM 4096
#define B_DIM 8
#define N_DIM 256
#define H_DIM 512
#define NT_DIM 5

typedef __attribute__((ext_vector_type(8))) short short8;
typedef __attribute__((ext_vector_type(4))) float f32x4;

__device__ __forceinline__ short cvt_bf16(float f) {
  __hip_bfloat16 h = __float2bfloat16(f);
  union { __hip_bfloat16 h; short s; } u; u.h = h; return u.s;
}
__device__ __forceinline__ float bf2f(short s) {
  union { uint32_t u; float f; } v; v.u = ((uint32_t)(uint16_t)s) << 16;
  return v.f;
}

// async global->LDS, 16B/lane; LDS dest = wave-uniform base + lane*16
typedef __attribute__((address_space(1))) const void gvoid_t;
typedef __attribute__((address_space(3))) void lvoid_t;
__device__ __forceinline__ void gl_lds16(const void* g, void* lds_wave_base) {
  __builtin_amdgcn_global_load_lds((gvoid_t*)(uintptr_t)g,
                                   (lvoid_t*)(uint32_t)(uintptr_t)lds_wave_base,
                                   16, 0, 0);
}

#define MFMA16(a, b, c) __builtin_amdgcn_mfma_f32_16x16x32_bf16(a, b, c, 0, 0, 0)

// dual-domain pointer set: dom = blockIdx.z >> zlog, zz = blockIdx.z & mask
struct GP {
  const void* A[2];
  const short* B[2];
  void* C[2];
  const float* R[2];
};

// ---------------------------------------------------------------------------
// TN GEMM: C[m,n] = scale * sum_k A[m,k] * Bt[n,k]  (+ Res[m,n])
// 128x128 tile, 4 waves, BK=32, 3-deep counted-vmcnt pipelines:
//  bf16 A/B: global_load_lds, vmcnt(8) steady (proven r7, out-proj 95->50us).
//  f32 A: A reg-loads 2-iter ahead + ds_write 1-iter ahead (A dbuf LDS),
//         B 3-deep global_load_lds; per-iter wait vmcnt(8) retires B(t).
// Epilogue: per-wave LDS restage -> coalesced dwordx4 IO, Res pipelined.
// ---------------------------------------------------------------------------
template<typename TA, typename TC, bool ADD_RES>
__global__ __launch_bounds__(256)
void gemm_tn(GP p, int zlog, long long a_bs, int lda,
             long long b_bs, int ldb, long long c_bs, int ldc,
             int K, float scale) {
  constexpr bool F32A = (sizeof(TA) == 4);
  constexpr int ASTR = F32A ? 40 : 32;
  constexpr int AB = 128 * ASTR * 2;     // bytes per A buffer
  constexpr int BB = 128 * 32 * 2;       // bytes per B buffer
  constexpr int HALF = AB + BB;          // bf16 combined buffer
  constexpr int EPIB = 4 * 16 * 68 * 4;
  constexpr int BODYB = F32A ? (2 * AB + 3 * BB) : (3 * HALF);
  constexpr int SMEMB = BODYB > EPIB ? BODYB : EPIB;
  __shared__ __align__(16) char smem[SMEMB];

  const int tid  = threadIdx.x;
  const int lane = tid & 63;
  const int wave = tid >> 6;
  const int wr   = (wave >> 1) * 64;
  const int wc   = (wave & 1) * 64;
  const int lrow = lane & 15;
  const int kgrp = lane >> 4;

  const int dom = blockIdx.z >> zlog;
  const long long zz = blockIdx.z & ((1u << zlog) - 1u);

  const TA*    Abase = (const TA*)p.A[dom] + zz * a_bs + (long long)(blockIdx.x * 128) * lda;
  const short* Bbase = p.B[dom] + zz * b_bs + (long long)(blockIdx.y * 128) * ldb;

  const int ch_r  = lane >> 2;
  const int swcol = ((lane & 3) ^ (ch_r & 3)) * 8;
  const int srow = tid >> 1;
  const int scol = (tid & 1) * 16;

  f32x4 acc[4][4] = {};
  f32x4 pv[4];

  // bf16 path: A at buf*HALF, B at buf*HALF+AB.  f32 path: A bufs at a*AB,
  // B bufs at 2*AB + b*BB.
  auto stageA_bf16 = [&](int buf, int k0) {
    short* As = (short*)(smem + buf * HALF);
    #pragma unroll
    for (int i = 0; i < 2; ++i) {
      const int c = wave + 4 * i;
      gl_lds16((const short*)Abase + (long long)(c * 16 + ch_r) * lda + k0 + swcol,
               &As[c * 512]);
    }
  };
  auto stageB_bf16 = [&](int buf, int k0) {
    short* Bs = (short*)(smem + buf * HALF + AB);
    #pragma unroll
    for (int i = 0; i < 2; ++i) {
      const int c = wave + 4 * i;
      gl_lds16(Bbase + (long long)(c * 16 + ch_r) * ldb + k0 + swcol, &Bs[c * 512]);
    }
  };
  auto stageB_f32p = [&](int buf, int k0) {
    short* Bs = (short*)(smem + 2 * AB + buf * BB);
    #pragma unroll
    for (int i = 0; i < 2; ++i) {
      const int c = wave + 4 * i;
      gl_lds16(Bbase + (long long)(c * 16 + ch_r) * ldb + k0 + swcol, &Bs[c * 512]);
    }
  };
  auto loadA_f32 = [&](int k0) {
    const float* gp = (const float*)Abase + (long long)srow * lda + k0 + scol;
    pv[0] = *(const f32x4*)(gp + 0);
    pv[1] = *(const f32x4*)(gp + 4);
    pv[2] = *(const f32x4*)(gp + 8);
    pv[3] = *(const f32x4*)(gp + 12);
  };
  auto writeA_f32 = [&](int buf) {
    short* As = (short*)(smem + buf * AB);
    short8 s0, s1;
    #pragma unroll
    for (int e = 0; e < 4; ++e) {
      s0[e]     = cvt_bf16(pv[0][e]);
      s0[4 + e] = cvt_bf16(pv[1][e]);
      s1[e]     = cvt_bf16(pv[2][e]);
      s1[4 + e] = cvt_bf16(pv[3][e]);
    }
    *(short8*)&As[srow * ASTR + scol]     = s0;
    *(short8*)&As[srow * ASTR + scol + 8] = s1;
  };
  auto compute = [&](int abuf, int bbuf) {
    const short* As = (const short*)(smem + (F32A ? abuf * AB : abuf * HALF));
    const short* Bs = (const short*)(smem + (F32A ? 2 * AB + bbuf * BB
                                                  : bbuf * HALF + AB));
    short8 af[4], bfr[4];
    const int u = kgrp ^ (lrow & 3);
    #pragma unroll
    for (int i = 0; i < 4; ++i) {
      const int row = wr + i * 16 + lrow;
      if constexpr (F32A) af[i] = *(const short8*)&As[row * ASTR + kgrp * 8];
      else                af[i] = *(const short8*)&As[row * 32 + u * 8];
    }
    #pragma unroll
    for (int j = 0; j < 4; ++j) {
      const int row = wc + j * 16 + lrow;
      bfr[j] = *(const short8*)&Bs[row * 32 + u * 8];
    }
    #pragma unroll
    for (int i = 0; i < 4; ++i)
      #pragma unroll
      for (int j = 0; j < 4; ++j)
        acc[i][j] = MFMA16(af[i], bfr[j], acc[i][j]);
  };

  const int NT = K >> 5;
  if constexpr (F32A) {
    // prologue: A(0) to LDS, B(0),B(1) staged, A(1) in regs
    loadA_f32(0); writeA_f32(0);
    stageB_f32p(0, 0);
    if (NT > 1) stageB_f32p(1, 32);
    if (NT > 1) loadA_f32(32);
    for (int t = 0; t < NT; ++t) {
      asm volatile("s_waitcnt lgkmcnt(0)" ::: "memory");
      __builtin_amdgcn_sched_barrier(0);
      __builtin_amdgcn_s_barrier();       // A(t) visible; B rotate safe
      if (t + 2 < NT) stageB_f32p((t + 2) % 3, (t + 2) << 5);
      __builtin_amdgcn_sched_barrier(0);
      if (t + 2 < NT)      asm volatile("s_waitcnt vmcnt(8)" ::: "memory");
      else if (t + 1 < NT) asm volatile("s_waitcnt vmcnt(6)" ::: "memory");
      else                 asm volatile("s_waitcnt vmcnt(0)" ::: "memory");
      __builtin_amdgcn_sched_barrier(0);
      __builtin_amdgcn_s_barrier();       // B(t) staged for all waves
      __builtin_amdgcn_sched_barrier(0);
      compute(t & 1, t % 3);
      if (t + 1 < NT) writeA_f32((t + 1) & 1);
      if (t + 2 < NT) loadA_f32((t + 2) << 5);
    }
  } else {
    // 3-deep counted-vmcnt pipeline (proven r7)
    stageA_bf16(0, 0); stageB_bf16(0, 0);
    if (NT > 1) { stageA_bf16(1, 32); stageB_bf16(1, 32); }
    for (int t = 0; t < NT; ++t) {
      __builtin_amdgcn_s_barrier();
      if (t + 2 < NT) {
        stageA_bf16((t + 2) % 3, (t + 2) << 5);
        stageB_bf16((t + 2) % 3, (t + 2) << 5);
        __builtin_amdgcn_sched_barrier(0);
        asm volatile("s_waitcnt vmcnt(8)" ::: "memory");
      } else if (t + 1 < NT) {
        asm volatile("s_waitcnt vmcnt(4)" ::: "memory");
      } else {
        asm volatile("s_waitcnt vmcnt(0)" ::: "memory");
      }
      __builtin_amdgcn_sched_barrier(0);
      __builtin_amdgcn_s_barrier();
      __builtin_amdgcn_sched_barrier(0);
      compute(t % 3, t % 3);
    }
  }

  // ---- epilogue ----
  __syncthreads();
  float* myEp = (float*)smem + wave * (16 * 68);
  TC* Cd = (TC*)p.C[dom];
  const float* Res = p.R[dom];
  const long long cb = zz * c_bs;
  const int gm = blockIdx.x * 128 + wr;
  const int gn = blockIdx.y * 128 + wc;
  const int er = lane >> 2;
  const int ec = (lane & 3) * 16;

  f32x4 resA[4], resB[4];
  if constexpr (ADD_RES) {
    const long long b0 = cb + (long long)(gm + er) * ldc + gn + ec;
    #pragma unroll
    for (int q = 0; q < 4; ++q) resA[q] = *(const f32x4*)&Res[b0 + q * 4];
  }

  #pragma unroll
  for (int i = 0; i < 4; ++i) {
    if constexpr (ADD_RES) {
      if (i < 3) {
        const long long bn = cb + (long long)(gm + (i + 1) * 16 + er) * ldc + gn + ec;
        #pragma unroll
        for (int q = 0; q < 4; ++q) resB[q] = *(const f32x4*)&Res[bn + q * 4];
      }
    }
    #pragma unroll
    for (int j = 0; j < 4; ++j)
      #pragma unroll
      for (int r = 0; r < 4; ++r)
        myEp[(kgrp * 4 + r) * 68 + j * 16 + lrow] = acc[i][j][r];
    float vals[16];
    #pragma unroll
    for (int q = 0; q < 4; ++q) {
      f32x4 t4 = *(const f32x4*)&myEp[er * 68 + ec + q * 4];
      vals[q * 4 + 0] = t4[0]; vals[q * 4 + 1] = t4[1];
      vals[q * 4 + 2] = t4[2]; vals[q * 4 + 3] = t4[3];
    }
    const int row_g = gm + i * 16 + er;
    const long long base = cb + (long long)row_g * ldc + gn + ec;
    if constexpr (sizeof(TC) == 2) {
      short8 s0, s1;
      #pragma unroll
      for (int e = 0; e < 8; ++e) {
        s0[e] = cvt_bf16(vals[e] * scale);
        s1[e] = cvt_bf16(vals[8 + e] * scale);
      }
      *(short8*)&Cd[base]     = s0;
      *(short8*)&Cd[base + 8] = s1;
    } else {
      #pragma unroll
      for (int q = 0; q < 4; ++q) {
        f32x4 o;
        #pragma unroll
        for (int e = 0; e < 4; ++e) o[e] = vals[q * 4 + e] * scale;
        if constexpr (ADD_RES) {
          #pragma unroll
          for (int e = 0; e < 4; ++e) o[e] += resA[q][e];
        }
        *(f32x4*)&Cd[base + q * 4] = o;
      }
    }
    if constexpr (ADD_RES) {
      #pragma unroll
      for (int q = 0; q < 4; ++q) resA[q] = resB[q];
    }
  }
}

// ---------------------------------------------------------------------------
// Weight transpose + cvt: WT[w][n][k] = bf16(W[w][k][n]), 8 matrices 512x512
// ---------------------------------------------------------------------------
struct WSrc { const float* p[8]; };

__global__ __launch_bounds__(256)
void wtrans_kernel(WSrc s, short* __restrict__ dst) {
  __shared__ float tile[32][33];
  const int w = blockIdx.z;
  const float* src = s.p[w];
  short* d = dst + (long long)w * H_DIM * H_DIM;
  const int tx = threadIdx.x, ty = threadIdx.y;
  const int n0 = blockIdx.x * 32, k0 = blockIdx.y * 32;
  #pragma unroll
  for (int i = 0; i < 4; ++i)
    tile[ty + 8 * i][tx] = src[(long long)(k0 + ty + 8 * i) * H_DIM + n0 + tx];
  __syncthreads();
  #pragma unroll
  for (int i = 0; i < 4; ++i)
    d[(long long)(n0 + ty + 8 * i) * H_DIM + k0 + tx] = cvt_bf16(tile[tx][ty + 8 * i]);
}

// ---------------------------------------------------------------------------
// Fused: combine + masked softmax + bf16 attn + nomask transpose to d_out.
// Grid (T/16, B), 256 thr. r=tid>>4 (t-row), seg=tid&15 (16-col slice).
// (round-6 proven version)
// ---------------------------------------------------------------------------
__global__ __launch_bounds__(256)
void softmax_fused(const short* __restrict__ Lv, const short* __restrict__ Lt,
                   const int* __restrict__ vmask, const int* __restrict__ tmask,
                   const float* __restrict__ vaw, const float* __restrict__ taw,
                   short* __restrict__ Av, short* __restrict__ At,
                   float* __restrict__ Onm_v, float* __restrict__ Onm_t) {
  __shared__ float tile[16 * 260];
  __shared__ int msk[2][256];
  const int tid = threadIdx.x;
  const int b = blockIdx.y, t0 = blockIdx.x * 16;
  const int r = tid >> 4, seg = tid & 15;
  msk[0][tid] = vmask[b * 256 + tid];
  msk[1][tid] = tmask[b * 256 + tid];
  __syncthreads();
  const float sv = 1.f / (1.f + __expf(-vaw[0]));
  const float st = 1.f / (1.f + __expf(-taw[0]));
  const long long off = ((long long)b * T_DIM + t0 + r) * N_DIM + seg * 16;

  short8 lv0 = *(const short8*)&Lv[off];
  short8 lv1 = *(const short8*)&Lv[off + 8];
  short8 lt0 = *(const short8*)&Lt[off];
  short8 lt1 = *(const short8*)&Lt[off + 8];
  float cv[16], ct[16];
  #pragma unroll
  for (int i = 0; i < 8; ++i) {
    float a0 = bf2f(lv0[i]), b0 = bf2f(lt0[i]);
    float a1 = bf2f(lv1[i]), b1 = bf2f(lt1[i]);
    cv[i]     = a0 + sv * b0;  ct[i]     = b0 + st * a0;
    cv[8 + i] = a1 + sv * b1;  ct[8 + i] = b1 + st * a1;
  }

#define EMIT_DOMAIN(CVAL, DI, AOUT, ONM) do {                                   \
    const int4 mA = *(const int4*)&msk[DI][seg * 16 + 0];                       \
    const int4 mB = *(const int4*)&msk[DI][seg * 16 + 4];                       \
    const int4 mC = *(const int4*)&msk[DI][seg * 16 + 8];                       \
    const int4 mD = *(const int4*)&msk[DI][seg * 16 + 12];                      \
    const int mk[16] = {mA.x, mA.y, mA.z, mA.w, mB.x, mB.y, mB.z, mB.w,         \
                        mC.x, mC.y, mC.z, mC.w, mD.x, mD.y, mD.z, mD.w};        \
    float mx = -3.4e38f;                                                        \
    _Pragma("unroll")                                                           \
    for (int q = 0; q < 16; ++q) if (mk[q] > 0) mx = fmaxf(mx, CVAL[q]);        \
    _Pragma("unroll")                                                           \
    for (int sh = 1; sh < 16; sh <<= 1) mx = fmaxf(mx, __shfl_xor(mx, sh));     \
    float ev[16]; float ssum = 0.f;                                             \
    _Pragma("unroll")                                                           \
    for (int q = 0; q < 16; ++q) {                                              \
      ev[q] = (mk[q] > 0) ? __expf(CVAL[q] - mx) : 0.f; ssum += ev[q];          \
    }                                                                           \
    _Pragma("unroll")                                                           \
    for (int sh = 1; sh < 16; sh <<= 1) ssum += __shfl_xor(ssum, sh);           \
    const float inv = 1.f / ssum;                                               \
    short8 o0, o1;                                                              \
    _Pragma("unroll")                                                           \
    for (int q = 0; q < 8; ++q) {                                               \
      o0[q] = cvt_bf16(ev[q] * inv); o1[q] = cvt_bf16(ev[8 + q] * inv);         \
    }                                                                           \
    *(short8*)&AOUT[off] = o0; *(short8*)&AOUT[off + 8] = o1;                   \
    _Pragma("unroll")                                                           \
    for (int q = 0; q < 4; ++q) {                                               \
      f32x4 tv; tv[0] = CVAL[q * 4]; tv[1] = CVAL[q * 4 + 1];                   \
      tv[2] = CVAL[q * 4 + 2]; tv[3] = CVAL[q * 4 + 3];                         \
      *(f32x4*)&tile[r * 260 + seg * 16 + q * 4] = tv;                          \
    }                                                                           \
    __syncthreads();                                                            \
    {                                                                           \
      float* obase = &ONM[((long long)b * N_DIM + tid) * T_DIM + t0];           \
      _Pragma("unroll")                                                         \
      for (int g = 0; g < 4; ++g) {                                             \
        f32x4 wv;                                                               \
        wv[0] = tile[(4 * g + 0) * 260 + tid];                                  \
        wv[1] = tile[(4 * g + 1) * 260 + tid];                                  \
        wv[2] = tile[(4 * g + 2) * 260 + tid];                                  \
        wv[3] = tile[(4 * g + 3) * 260 + tid];                                  \
        *(f32x4*)&obase[4 * g] = wv;                                            \
      }                                                                         \
    }                                                                           \
    __syncthreads();                                                            \
  } while (0)

  EMIT_DOMAIN(cv, 0, Av, Onm_v);
  EMIT_DOMAIN(ct, 1, At, Onm_t);
#undef EMIT_DOMAIN
}

// ---------------------------------------------------------------------------
// Task heads
// ---------------------------------------------------------------------------
__global__ __launch_bounds__(1024)
void task_kernel(const float* __restrict__ vtask, const float* __restrict__ ttask,
                 const float* __restrict__ vtw, const float* __restrict__ vtb,
                 const float* __restrict__ ttw, const float* __restrict__ ttb,
                 float* __restrict__ out_v, float* __restrict__ out_t) {
  const int wave = threadIdx.x >> 6;
  const int lane = threadIdx.x & 63;
  const int dom = wave >> 3;
  const int b   = wave & 7;
  const float* task = dom ? ttask : vtask;
  const float* tw   = dom ? ttw : vtw;
  const float  tb   = (dom ? ttb : vtb)[0];
  float* o = dom ? out_t : out_v;
  for (int k = 0; k < NT_DIM; ++k) {
    const float* row = task + ((long long)k * B_DIM + b) * H_DIM;
    float s = 0.f;
    for (int c = lane; c < H_DIM; c += 64) s += row[c] * tw[c];
    #pragma unroll
    for (int d = 32; d > 0; d >>= 1) s += __shfl_xor(s, d);
    if (lane == 0) o[k * B_DIM + b] = s + tb;
  }
}

// ---------------------------------------------------------------------------
extern "C" void kernel_launch(void* const* d_in, const int* in_sizes, int n_in,
                              void* d_out, int out_size, void* d_ws, size_t ws_size,
                              hipStream_t stream) {
  const float* v_action = (const float*)d_in[0];
  const float* v_frame  = (const float*)d_in[1];
  const float* v_task   = (const float*)d_in[2];
  const int*   v_mask   = (const int*)d_in[3];
  const float* t_action = (const float*)d_in[4];
  const float* t_frame  = (const float*)d_in[5];
  const float* t_task   = (const float*)d_in[6];
  const int*   t_mask   = (const int*)d_in[7];
  const float* v_aw = (const float*)d_in[16];
  const float* t_aw = (const float*)d_in[17];
  const float* v_tw = (const float*)d_in[18];
  const float* v_tb = (const float*)d_in[19];
  const float* t_tw = (const float*)d_in[20];
  const float* t_tb = (const float*)d_in[21];

  const long long TBH = (long long)T_DIM * B_DIM * H_DIM;
  const long long BTN = (long long)B_DIM * T_DIM * N_DIM;
  const long long NBH = (long long)N_DIM * B_DIM * H_DIM;
  const long long WS  = (long long)H_DIM * H_DIM;

  float* out = (float*)d_out;
  float* out_v   = out;
  float* out_t   = out + TBH;
  float* out_vnm = out + 2 * TBH;
  float* out_tnm = out + 2 * TBH + BTN;
  float* out_vta = out + 2 * TBH + 2 * BTN;
  float* out_tta = out_vta + NT_DIM * B_DIM;

  char* w = (char*)d_ws;
  auto alloc = [&](long long bytes) {
    char* p = w; w += (bytes + 255) & ~255LL; return p;
  };
  short* WT   = (short*)alloc(8 * WS * 2);
  short* Qv   = (short*)alloc(TBH * 2);
  short* Qt   = (short*)alloc(TBH * 2);
  short* KVv  = (short*)alloc(2048LL * 1024 * 2);
  short* KVt  = (short*)alloc(2048LL * 1024 * 2);
  short* VWTv = (short*)alloc(NBH * 2);    // (V@Wo)^T per b: [b][h][n]
  short* VWTt = (short*)alloc(NBH * 2);
  short* Av   = (short*)alloc(BTN * 2);
  short* At   = (short*)alloc(BTN * 2);
  short* Lv   = (short*)alloc(BTN * 2);
  short* Lt   = (short*)alloc(BTN * 2);

  const float rsq = 0.044194173824159216f;  // 1/sqrt(512)

  // 1. weight transpose + cvt
  WSrc ws8;
  for (int i = 0; i < 8; ++i) ws8.p[i] = (const float*)d_in[8 + i];
  wtrans_kernel<<<dim3(16, 16, 8), dim3(32, 8), 0, stream>>>(ws8, WT);

  // 2. Q projections (f32 A, 3-deep pipeline), both domains
  {
    GP p = {{v_frame, t_frame}, {WT + 0 * WS, WT + 4 * WS}, {Qv, Qt}, {nullptr, nullptr}};
    gemm_tn<float, short, false><<<dim3(256, 4, 2), dim3(256), 0, stream>>>(
        p, 0, 0LL, H_DIM, 0LL, H_DIM, 0LL, H_DIM, 512, 1.f);
  }

  // 3. merged K|V projections, both domains
  {
    GP p = {{v_action, t_action}, {WT + 1 * WS, WT + 5 * WS}, {KVv, KVt}, {nullptr, nullptr}};
    gemm_tn<float, short, false><<<dim3(16, 8, 2), dim3(256), 0, stream>>>(
        p, 0, 0LL, H_DIM, 0LL, H_DIM, 0LL, 1024, 512, 1.f);
  }

  // 4. VWT[b][h][n] = (V@Wo)^T
  {
    GP p = {{WT + 3 * WS, WT + 7 * WS}, {KVv + 512, KVt + 512}, {VWTv, VWTt},
            {nullptr, nullptr}};
    gemm_tn<short, short, false><<<dim3(4, 2, 16), dim3(256), 0, stream>>>(
        p, 3, 0LL, H_DIM, 1024LL, 8192, (long long)H_DIM * N_DIM, N_DIM, 512, 1.f);
  }

  // 5. logits (bf16 out) [B,T,N], both domains (z = dom*8 + b)
  {
    GP p = {{Qv, Qt}, {KVv, KVt}, {Lv, Lt}, {nullptr, nullptr}};
    gemm_tn<short, short, false><<<dim3(32, 2, 16), dim3(256), 0, stream>>>(
        p, 3, 512LL, B_DIM * H_DIM, 1024LL, 8192,
        (long long)T_DIM * N_DIM, N_DIM, 512, rsq);
  }

  // 6. fused combine + softmax + nomask-transpose (writes out_nm directly)
  softmax_fused<<<dim3(T_DIM / 16, B_DIM), dim3(256), 0, stream>>>(
      Lv, Lt, v_mask, t_mask, v_aw, t_aw, Av, At, out_vnm, out_tnm);

  // 7. out = attn @ VW + frame  (K=256)
  {
    GP p = {{Av, At}, {VWTv, VWTt}, {out_v, out_t}, {v_frame, t_frame}};
    gemm_tn<short, float, true><<<dim3(32, 4, 16), dim3(256), 0, stream>>>(
        p, 3, (long long)T_DIM * N_DIM, N_DIM, (long long)H_DIM * N_DIM, N_DIM,
        512LL, B_DIM * H_DIM, 256, 1.f);
  }

  // 8. task heads
  task_kernel<<<dim3(1), dim3(1024), 0, stream>>>(
      v_task, t_task, v_tw, v_tb, t_tw, t_tb, out_vta, out_tta);
}

// Round 9
// 245.963 us; speedup vs baseline: 1.2717x; 1.1801x over previous
//
#include <hip/hip_runtime.h>
#include <hip/hip_bf16.h>
#include <cstddef>
#include <cstdint>

#define T_DIM 4096
#define B_DIM 8
#define N_DIM 256
#define H_DIM 512
#define NT_DIM 5

typedef __attribute__((ext_vector_type(8))) short short8;
typedef __attribute__((ext_vector_type(4))) float f32x4;

__device__ __forceinline__ short cvt_bf16(float f) {
  __hip_bfloat16 h = __float2bfloat16(f);
  union { __hip_bfloat16 h; short s; } u; u.h = h; return u.s;
}
__device__ __forceinline__ float bf2f(short s) {
  union { uint32_t u; float f; } v; v.u = ((uint32_t)(uint16_t)s) << 16;
  return v.f;
}

// async global->LDS, 16B/lane; LDS dest = wave-uniform base + lane*16
typedef __attribute__((address_space(1))) const void gvoid_t;
typedef __attribute__((address_space(3))) void lvoid_t;
__device__ __forceinline__ void gl_lds16(const void* g, void* lds_wave_base) {
  __builtin_amdgcn_global_load_lds((gvoid_t*)(uintptr_t)g,
                                   (lvoid_t*)(uint32_t)(uintptr_t)lds_wave_base,
                                   16, 0, 0);
}

#define MFMA16(a, b, c) __builtin_amdgcn_mfma_f32_16x16x32_bf16(a, b, c, 0, 0, 0)

// multi-slot pointer set: slot = blockIdx.z >> zlog, zz = blockIdx.z & mask
struct GP {
  const void* A[4];
  const short* B[4];
  void* C[4];
  const float* R[4];
};

// ---------------------------------------------------------------------------
// TN GEMM: C[m,n] = scale * sum_k A[m,k] * Bt[n,k]  (+ Res[m,n])
// 128x128 tile, 4 waves, BK=32, 3-deep counted-vmcnt pipelines (proven r7/r8).
// ---------------------------------------------------------------------------
template<typename TA, typename TC, bool ADD_RES>
__global__ __launch_bounds__(256)
void gemm_tn(GP p, int zlog, long long a_bs, int lda,
             long long b_bs, int ldb, long long c_bs, int ldc,
             int K, float scale) {
  constexpr bool F32A = (sizeof(TA) == 4);
  constexpr int ASTR = F32A ? 40 : 32;
  constexpr int AB = 128 * ASTR * 2;
  constexpr int BB = 128 * 32 * 2;
  constexpr int HALF = AB + BB;
  constexpr int EPIB = 4 * 16 * 68 * 4;
  constexpr int BODYB = F32A ? (2 * AB + 3 * BB) : (3 * HALF);
  constexpr int SMEMB = BODYB > EPIB ? BODYB : EPIB;
  __shared__ __align__(16) char smem[SMEMB];

  const int tid  = threadIdx.x;
  const int lane = tid & 63;
  const int wave = tid >> 6;
  const int wr   = (wave >> 1) * 64;
  const int wc   = (wave & 1) * 64;
  const int lrow = lane & 15;
  const int kgrp = lane >> 4;

  const int dom = blockIdx.z >> zlog;
  const long long zz = blockIdx.z & ((1u << zlog) - 1u);

  const TA*    Abase = (const TA*)p.A[dom] + zz * a_bs + (long long)(blockIdx.x * 128) * lda;
  const short* Bbase = p.B[dom] + zz * b_bs + (long long)(blockIdx.y * 128) * ldb;

  const int ch_r  = lane >> 2;
  const int swcol = ((lane & 3) ^ (ch_r & 3)) * 8;
  const int srow = tid >> 1;
  const int scol = (tid & 1) * 16;

  f32x4 acc[4][4] = {};
  f32x4 pv[4];

  auto stageA_bf16 = [&](int buf, int k0) {
    short* As = (short*)(smem + buf * HALF);
    #pragma unroll
    for (int i = 0; i < 2; ++i) {
      const int c = wave + 4 * i;
      gl_lds16((const short*)Abase + (long long)(c * 16 + ch_r) * lda + k0 + swcol,
               &As[c * 512]);
    }
  };
  auto stageB_bf16 = [&](int buf, int k0) {
    short* Bs = (short*)(smem + buf * HALF + AB);
    #pragma unroll
    for (int i = 0; i < 2; ++i) {
      const int c = wave + 4 * i;
      gl_lds16(Bbase + (long long)(c * 16 + ch_r) * ldb + k0 + swcol, &Bs[c * 512]);
    }
  };
  auto stageB_f32p = [&](int buf, int k0) {
    short* Bs = (short*)(smem + 2 * AB + buf * BB);
    #pragma unroll
    for (int i = 0; i < 2; ++i) {
      const int c = wave + 4 * i;
      gl_lds16(Bbase + (long long)(c * 16 + ch_r) * ldb + k0 + swcol, &Bs[c * 512]);
    }
  };
  auto loadA_f32 = [&](int k0) {
    const float* gp = (const float*)Abase + (long long)srow * lda + k0 + scol;
    pv[0] = *(const f32x4*)(gp + 0);
    pv[1] = *(const f32x4*)(gp + 4);
    pv[2] = *(const f32x4*)(gp + 8);
    pv[3] = *(const f32x4*)(gp + 12);
  };
  auto writeA_f32 = [&](int buf) {
    short* As = (short*)(smem + buf * AB);
    short8 s0, s1;
    #pragma unroll
    for (int e = 0; e < 4; ++e) {
      s0[e]     = cvt_bf16(pv[0][e]);
      s0[4 + e] = cvt_bf16(pv[1][e]);
      s1[e]     = cvt_bf16(pv[2][e]);
      s1[4 + e] = cvt_bf16(pv[3][e]);
    }
    *(short8*)&As[srow * ASTR + scol]     = s0;
    *(short8*)&As[srow * ASTR + scol + 8] = s1;
  };
  auto compute = [&](int abuf, int bbuf) {
    const short* As = (const short*)(smem + (F32A ? abuf * AB : abuf * HALF));
    const short* Bs = (const short*)(smem + (F32A ? 2 * AB + bbuf * BB
                                                  : bbuf * HALF + AB));
    short8 af[4], bfr[4];
    const int u = kgrp ^ (lrow & 3);
    #pragma unroll
    for (int i = 0; i < 4; ++i) {
      const int row = wr + i * 16 + lrow;
      if constexpr (F32A) af[i] = *(const short8*)&As[row * ASTR + kgrp * 8];
      else                af[i] = *(const short8*)&As[row * 32 + u * 8];
    }
    #pragma unroll
    for (int j = 0; j < 4; ++j) {
      const int row = wc + j * 16 + lrow;
      bfr[j] = *(const short8*)&Bs[row * 32 + u * 8];
    }
    #pragma unroll
    for (int i = 0; i < 4; ++i)
      #pragma unroll
      for (int j = 0; j < 4; ++j)
        acc[i][j] = MFMA16(af[i], bfr[j], acc[i][j]);
  };

  const int NT = K >> 5;
  if constexpr (F32A) {
    loadA_f32(0); writeA_f32(0);
    stageB_f32p(0, 0);
    if (NT > 1) stageB_f32p(1, 32);
    if (NT > 1) loadA_f32(32);
    for (int t = 0; t < NT; ++t) {
      asm volatile("s_waitcnt lgkmcnt(0)" ::: "memory");
      __builtin_amdgcn_sched_barrier(0);
      __builtin_amdgcn_s_barrier();       // A(t) visible; B rotate safe
      if (t + 2 < NT) stageB_f32p((t + 2) % 3, (t + 2) << 5);
      __builtin_amdgcn_sched_barrier(0);
      if (t + 2 < NT)      asm volatile("s_waitcnt vmcnt(8)" ::: "memory");
      else if (t + 1 < NT) asm volatile("s_waitcnt vmcnt(6)" ::: "memory");
      else                 asm volatile("s_waitcnt vmcnt(0)" ::: "memory");
      __builtin_amdgcn_sched_barrier(0);
      __builtin_amdgcn_s_barrier();       // B(t) staged for all waves
      __builtin_amdgcn_sched_barrier(0);
      compute(t & 1, t % 3);
      if (t + 1 < NT) writeA_f32((t + 1) & 1);
      if (t + 2 < NT) loadA_f32((t + 2) << 5);
    }
  } else {
    stageA_bf16(0, 0); stageB_bf16(0, 0);
    if (NT > 1) { stageA_bf16(1, 32); stageB_bf16(1, 32); }
    for (int t = 0; t < NT; ++t) {
      __builtin_amdgcn_s_barrier();
      if (t + 2 < NT) {
        stageA_bf16((t + 2) % 3, (t + 2) << 5);
        stageB_bf16((t + 2) % 3, (t + 2) << 5);
        __builtin_amdgcn_sched_barrier(0);
        asm volatile("s_waitcnt vmcnt(8)" ::: "memory");
      } else if (t + 1 < NT) {
        asm volatile("s_waitcnt vmcnt(4)" ::: "memory");
      } else {
        asm volatile("s_waitcnt vmcnt(0)" ::: "memory");
      }
      __builtin_amdgcn_sched_barrier(0);
      __builtin_amdgcn_s_barrier();
      __builtin_amdgcn_sched_barrier(0);
      compute(t % 3, t % 3);
    }
  }

  // ---- epilogue ----
  __syncthreads();
  float* myEp = (float*)smem + wave * (16 * 68);
  TC* Cd = (TC*)p.C[dom];
  const float* Res = p.R[dom];
  const long long cb = zz * c_bs;
  const int gm = blockIdx.x * 128 + wr;
  const int gn = blockIdx.y * 128 + wc;
  const int er = lane >> 2;
  const int ec = (lane & 3) * 16;

  f32x4 resA[4], resB[4];
  if constexpr (ADD_RES) {
    const long long b0 = cb + (long long)(gm + er) * ldc + gn + ec;
    #pragma unroll
    for (int q = 0; q < 4; ++q) resA[q] = *(const f32x4*)&Res[b0 + q * 4];
  }

  #pragma unroll
  for (int i = 0; i < 4; ++i) {
    if constexpr (ADD_RES) {
      if (i < 3) {
        const long long bn = cb + (long long)(gm + (i + 1) * 16 + er) * ldc + gn + ec;
        #pragma unroll
        for (int q = 0; q < 4; ++q) resB[q] = *(const f32x4*)&Res[bn + q * 4];
      }
    }
    #pragma unroll
    for (int j = 0; j < 4; ++j)
      #pragma unroll
      for (int r = 0; r < 4; ++r)
        myEp[(kgrp * 4 + r) * 68 + j * 16 + lrow] = acc[i][j][r];
    float vals[16];
    #pragma unroll
    for (int q = 0; q < 4; ++q) {
      f32x4 t4 = *(const f32x4*)&myEp[er * 68 + ec + q * 4];
      vals[q * 4 + 0] = t4[0]; vals[q * 4 + 1] = t4[1];
      vals[q * 4 + 2] = t4[2]; vals[q * 4 + 3] = t4[3];
    }
    const int row_g = gm + i * 16 + er;
    const long long base = cb + (long long)row_g * ldc + gn + ec;
    if constexpr (sizeof(TC) == 2) {
      short8 s0, s1;
      #pragma unroll
      for (int e = 0; e < 8; ++e) {
        s0[e] = cvt_bf16(vals[e] * scale);
        s1[e] = cvt_bf16(vals[8 + e] * scale);
      }
      *(short8*)&Cd[base]     = s0;
      *(short8*)&Cd[base + 8] = s1;
    } else {
      #pragma unroll
      for (int q = 0; q < 4; ++q) {
        f32x4 o;
        #pragma unroll
        for (int e = 0; e < 4; ++e) o[e] = vals[q * 4 + e] * scale;
        if constexpr (ADD_RES) {
          #pragma unroll
          for (int e = 0; e < 4; ++e) o[e] += resA[q][e];
        }
        *(f32x4*)&Cd[base + q * 4] = o;
      }
    }
    if constexpr (ADD_RES) {
      #pragma unroll
      for (int q = 0; q < 4; ++q) resA[q] = resB[q];
    }
  }
}

// ---------------------------------------------------------------------------
// Raw f32->bf16 copy of 6 weight matrices (Wq,Wk,Wv both domains)
// ---------------------------------------------------------------------------
struct W6 { const float* p[6]; };

__global__ __launch_bounds__(256)
void rawcvt_kernel(W6 s, short* __restrict__ dst) {
  const int w = blockIdx.y;
  const float* src = s.p[w];
  short* d = dst + (long long)w * H_DIM * H_DIM;
  const int i = (blockIdx.x * 256 + threadIdx.x) * 8;   // grid.x = 128
  f32x4 v0 = *(const f32x4*)(src + i);
  f32x4 v1 = *(const f32x4*)(src + i + 4);
  short8 o;
  #pragma unroll
  for (int e = 0; e < 4; ++e) { o[e] = cvt_bf16(v0[e]); o[4 + e] = cvt_bf16(v1[e]); }
  *(short8*)&d[i] = o;
}

// ---------------------------------------------------------------------------
// Transposed cvt for Wo (2 matrices): WoT[n][k] = bf16(Wo[k][n])
// ---------------------------------------------------------------------------
struct W2 { const float* p[2]; };

__global__ __launch_bounds__(256)
void wtrans_kernel(W2 s, short* __restrict__ dst) {
  __shared__ float tile[32][33];
  const int w = blockIdx.z;
  const float* src = s.p[w];
  short* d = dst + (long long)w * H_DIM * H_DIM;
  const int tx = threadIdx.x, ty = threadIdx.y;
  const int n0 = blockIdx.x * 32, k0 = blockIdx.y * 32;
  #pragma unroll
  for (int i = 0; i < 4; ++i)
    tile[ty + 8 * i][tx] = src[(long long)(k0 + ty + 8 * i) * H_DIM + n0 + tx];
  __syncthreads();
  #pragma unroll
  for (int i = 0; i < 4; ++i)
    d[(long long)(n0 + ty + 8 * i) * H_DIM + k0 + tx] = cvt_bf16(tile[tx][ty + 8 * i]);
}

// ---------------------------------------------------------------------------
// action f32 -> bf16 (layout preserved), both domains
// ---------------------------------------------------------------------------
__global__ __launch_bounds__(256)
void ac16_kernel(const float* __restrict__ av, const float* __restrict__ at,
                 short* __restrict__ ov, short* __restrict__ ot) {
  const int dom = blockIdx.y;
  const float* src = dom ? at : av;
  short* d = dom ? ot : ov;
  const int i = (blockIdx.x * 256 + threadIdx.x) * 8;   // grid.x = 512
  f32x4 v0 = *(const f32x4*)(src + i);
  f32x4 v1 = *(const f32x4*)(src + i + 4);
  short8 o;
  #pragma unroll
  for (int e = 0; e < 4; ++e) { o[e] = cvt_bf16(v0[e]); o[4 + e] = cvt_bf16(v1[e]); }
  *(short8*)&d[i] = o;
}

// ---------------------------------------------------------------------------
// Fused: combine + masked softmax + bf16 attn + nomask transpose (r6 proven)
// ---------------------------------------------------------------------------
__global__ __launch_bounds__(256)
void softmax_fused(const short* __restrict__ Lv, const short* __restrict__ Lt,
                   const int* __restrict__ vmask, const int* __restrict__ tmask,
                   const float* __restrict__ vaw, const float* __restrict__ taw,
                   short* __restrict__ Av, short* __restrict__ At,
                   float* __restrict__ Onm_v, float* __restrict__ Onm_t) {
  __shared__ float tile[16 * 260];
  __shared__ int msk[2][256];
  const int tid = threadIdx.x;
  const int b = blockIdx.y, t0 = blockIdx.x * 16;
  const int r = tid >> 4, seg = tid & 15;
  msk[0][tid] = vmask[b * 256 + tid];
  msk[1][tid] = tmask[b * 256 + tid];
  __syncthreads();
  const float sv = 1.f / (1.f + __expf(-vaw[0]));
  const float st = 1.f / (1.f + __expf(-taw[0]));
  const long long off = ((long long)b * T_DIM + t0 + r) * N_DIM + seg * 16;

  short8 lv0 = *(const short8*)&Lv[off];
  short8 lv1 = *(const short8*)&Lv[off + 8];
  short8 lt0 = *(const short8*)&Lt[off];
  short8 lt1 = *(const short8*)&Lt[off + 8];
  float cv[16], ct[16];
  #pragma unroll
  for (int i = 0; i < 8; ++i) {
    float a0 = bf2f(lv0[i]), b0 = bf2f(lt0[i]);
    float a1 = bf2f(lv1[i]), b1 = bf2f(lt1[i]);
    cv[i]     = a0 + sv * b0;  ct[i]     = b0 + st * a0;
    cv[8 + i] = a1 + sv * b1;  ct[8 + i] = b1 + st * a1;
  }

#define EMIT_DOMAIN(CVAL, DI, AOUT, ONM) do {                                   \
    const int4 mA = *(const int4*)&msk[DI][seg * 16 + 0];                       \
    const int4 mB = *(const int4*)&msk[DI][seg * 16 + 4];                       \
    const int4 mC = *(const int4*)&msk[DI][seg * 16 + 8];                       \
    const int4 mD = *(const int4*)&msk[DI][seg * 16 + 12];                      \
    const int mk[16] = {mA.x, mA.y, mA.z, mA.w, mB.x, mB.y, mB.z, mB.w,         \
                        mC.x, mC.y, mC.z, mC.w, mD.x, mD.y, mD.z, mD.w};        \
    float mx = -3.4e38f;                                                        \
    _Pragma("unroll")                                                           \
    for (int q = 0; q < 16; ++q) if (mk[q] > 0) mx = fmaxf(mx, CVAL[q]);        \
    _Pragma("unroll")                                                           \
    for (int sh = 1; sh < 16; sh <<= 1) mx = fmaxf(mx, __shfl_xor(mx, sh));     \
    float ev[16]; float ssum = 0.f;                                             \
    _Pragma("unroll")                                                           \
    for (int q = 0; q < 16; ++q) {                                              \
      ev[q] = (mk[q] > 0) ? __expf(CVAL[q] - mx) : 0.f; ssum += ev[q];          \
    }                                                                           \
    _Pragma("unroll")                                                           \
    for (int sh = 1; sh < 16; sh <<= 1) ssum += __shfl_xor(ssum, sh);           \
    const float inv = 1.f / ssum;                                               \
    short8 o0, o1;                                                              \
    _Pragma("unroll")                                                           \
    for (int q = 0; q < 8; ++q) {                                               \
      o0[q] = cvt_bf16(ev[q] * inv); o1[q] = cvt_bf16(ev[8 + q] * inv);         \
    }                                                                           \
    *(short8*)&AOUT[off] = o0; *(short8*)&AOUT[off + 8] = o1;                   \
    _Pragma("unroll")                                                           \
    for (int q = 0; q < 4; ++q) {                                               \
      f32x4 tv; tv[0] = CVAL[q * 4]; tv[1] = CVAL[q * 4 + 1];                   \
      tv[2] = CVAL[q * 4 + 2]; tv[3] = CVAL[q * 4 + 3];                         \
      *(f32x4*)&tile[r * 260 + seg * 16 + q * 4] = tv;                          \
    }                                                                           \
    __syncthreads();                                                            \
    {                                                                           \
      float* obase = &ONM[((long long)b * N_DIM + tid) * T_DIM + t0];           \
      _Pragma("unroll")                                                         \
      for (int g = 0; g < 4; ++g) {                                             \
        f32x4 wv;                                                               \
        wv[0] = tile[(4 * g + 0) * 260 + tid];                                  \
        wv[1] = tile[(4 * g + 1) * 260 + tid];                                  \
        wv[2] = tile[(4 * g + 2) * 260 + tid];                                  \
        wv[3] = tile[(4 * g + 3) * 260 + tid];                                  \
        *(f32x4*)&obase[4 * g] = wv;                                            \
      }                                                                         \
    }                                                                           \
    __syncthreads();                                                            \
  } while (0)

  EMIT_DOMAIN(cv, 0, Av, Onm_v);
  EMIT_DOMAIN(ct, 1, At, Onm_t);
#undef EMIT_DOMAIN
}

// ---------------------------------------------------------------------------
// Task heads
// ---------------------------------------------------------------------------
__global__ __launch_bounds__(1024)
void task_kernel(const float* __restrict__ vtask, const float* __restrict__ ttask,
                 const float* __restrict__ vtw, const float* __restrict__ vtb,
                 const float* __restrict__ ttw, const float* __restrict__ ttb,
                 float* __restrict__ out_v, float* __restrict__ out_t) {
  const int wave = threadIdx.x >> 6;
  const int lane = threadIdx.x & 63;
  const int dom = wave >> 3;
  const int b   = wave & 7;
  const float* task = dom ? ttask : vtask;
  const float* tw   = dom ? ttw : vtw;
  const float  tb   = (dom ? ttb : vtb)[0];
  float* o = dom ? out_t : out_v;
  for (int k = 0; k < NT_DIM; ++k) {
    const float* row = task + ((long long)k * B_DIM + b) * H_DIM;
    float s = 0.f;
    for (int c = lane; c < H_DIM; c += 64) s += row[c] * tw[c];
    #pragma unroll
    for (int d = 32; d > 0; d >>= 1) s += __shfl_xor(s, d);
    if (lane == 0) o[k * B_DIM + b] = s + tb;
  }
}

// ---------------------------------------------------------------------------
extern "C" void kernel_launch(void* const* d_in, const int* in_sizes, int n_in,
                              void* d_out, int out_size, void* d_ws, size_t ws_size,
                              hipStream_t stream) {
  const float* v_action = (const float*)d_in[0];
  const float* v_frame  = (const float*)d_in[1];
  const float* v_task   = (const float*)d_in[2];
  const int*   v_mask   = (const int*)d_in[3];
  const float* t_action = (const float*)d_in[4];
  const float* t_frame  = (const float*)d_in[5];
  const float* t_task   = (const float*)d_in[6];
  const int*   t_mask   = (const int*)d_in[7];
  const float* v_aw = (const float*)d_in[16];
  const float* t_aw = (const float*)d_in[17];
  const float* v_tw = (const float*)d_in[18];
  const float* v_tb = (const float*)d_in[19];
  const float* t_tw = (const float*)d_in[20];
  const float* t_tb = (const float*)d_in[21];

  const long long TBH = (long long)T_DIM * B_DIM * H_DIM;
  const long long BTN = (long long)B_DIM * T_DIM * N_DIM;
  const long long WS  = (long long)H_DIM * H_DIM;     // 262144

  float* out = (float*)d_out;
  float* out_v   = out;
  float* out_t   = out + TBH;
  float* out_vnm = out + 2 * TBH;
  float* out_tnm = out + 2 * TBH + BTN;
  float* out_vta = out + 2 * TBH + 2 * BTN;
  float* out_tta = out_vta + NT_DIM * B_DIM;

  char* w = (char*)d_ws;
  auto alloc = [&](long long bytes) {
    char* p = w; w += (bytes + 255) & ~255LL; return p;
  };
  // WT slots: 0 WQv,1 WKv,2 WVv,3 WQt,4 WKt,5 WVt (raw), 6 WoTv,7 WoTt (trans)
  short* WT    = (short*)alloc(8 * WS * 2);
  short* Mv    = (short*)alloc(WS * 2);
  short* Mt    = (short*)alloc(WS * 2);
  short* PTv   = (short*)alloc(WS * 2);
  short* PTt   = (short*)alloc(WS * 2);
  short* Ac16v = (short*)alloc(1048576LL * 2);
  short* Ac16t = (short*)alloc(1048576LL * 2);
  short* KWTv  = (short*)alloc(8LL * 131072 * 2);  // [b][n][f]
  short* KWTt  = (short*)alloc(8LL * 131072 * 2);
  short* VWTv  = (short*)alloc(8LL * 131072 * 2);  // [b][g][n]
  short* VWTt  = (short*)alloc(8LL * 131072 * 2);
  short* Av    = (short*)alloc(BTN * 2);
  short* At    = (short*)alloc(BTN * 2);
  short* Lv    = (short*)alloc(BTN * 2);
  short* Lt    = (short*)alloc(BTN * 2);

  const float rsq = 0.044194173824159216f;  // 1/sqrt(512)

  // 1. weight prep: raw cvt (Wq,Wk,Wv x2) + transposed Wo x2
  {
    W6 s6 = {{(const float*)d_in[8], (const float*)d_in[9], (const float*)d_in[10],
              (const float*)d_in[12], (const float*)d_in[13], (const float*)d_in[14]}};
    rawcvt_kernel<<<dim3(128, 6), dim3(256), 0, stream>>>(s6, WT);
    W2 s2 = {{(const float*)d_in[11], (const float*)d_in[15]}};
    wtrans_kernel<<<dim3(16, 16, 2), dim3(32, 8), 0, stream>>>(s2, WT + 6 * WS);
  }

  // 2. action -> bf16
  ac16_kernel<<<dim3(512, 2), dim3(256), 0, stream>>>(v_action, t_action, Ac16v, Ac16t);

  // 3. M = Wq@Wk^T and PT = WoT@Wv, 4 slots in one launch (z=0..3, zlog=0)
  {
    GP p = {{WT + 0 * WS, WT + 3 * WS, WT + 6 * WS, WT + 7 * WS},
            {WT + 1 * WS, WT + 4 * WS, WT + 2 * WS, WT + 5 * WS},
            {Mv, Mt, PTv, PTt},
            {nullptr, nullptr, nullptr, nullptr}};
    gemm_tn<short, short, false><<<dim3(4, 4, 4), dim3(256), 0, stream>>>(
        p, 0, 0LL, H_DIM, 0LL, H_DIM, 0LL, H_DIM, 512, 1.f);
  }

  // 4. KWT[b][n][f] = action @ M^T  (z = dom*8+b)
  {
    GP p = {{Ac16v, Ac16t}, {Mv, Mt}, {KWTv, KWTt}, {nullptr, nullptr}};
    gemm_tn<short, short, false><<<dim3(2, 4, 16), dim3(256), 0, stream>>>(
        p, 3, 512LL, B_DIM * H_DIM, 0LL, H_DIM, 131072LL, H_DIM, 512, 1.f);
  }

  // 5. VWT[b][g][n] = PT @ action^T  (z = dom*8+b)
  {
    GP p = {{PTv, PTt}, {Ac16v, Ac16t}, {VWTv, VWTt}, {nullptr, nullptr}};
    gemm_tn<short, short, false><<<dim3(4, 2, 16), dim3(256), 0, stream>>>(
        p, 3, 0LL, H_DIM, 512LL, B_DIM * H_DIM, 131072LL, N_DIM, 512, 1.f);
  }

  // 6. logits (bf16) [B,T,N] = frame @ KWT^T  (f32-A path; z = dom*8+b)
  {
    GP p = {{v_frame, t_frame}, {KWTv, KWTt}, {Lv, Lt}, {nullptr, nullptr}};
    gemm_tn<float, short, false><<<dim3(32, 2, 16), dim3(256), 0, stream>>>(
        p, 3, 512LL, B_DIM * H_DIM, 131072LL, H_DIM,
        (long long)T_DIM * N_DIM, N_DIM, 512, rsq);
  }

  // 7. fused combine + softmax + nomask-transpose
  softmax_fused<<<dim3(T_DIM / 16, B_DIM), dim3(256), 0, stream>>>(
      Lv, Lt, v_mask, t_mask, v_aw, t_aw, Av, At, out_vnm, out_tnm);

  // 8. out = attn @ VW + frame  (K=256)
  {
    GP p = {{Av, At}, {VWTv, VWTt}, {out_v, out_t}, {v_frame, t_frame}};
    gemm_tn<short, float, true><<<dim3(32, 4, 16), dim3(256), 0, stream>>>(
        p, 3, (long long)T_DIM * N_DIM, N_DIM, 131072LL, N_DIM,
        512LL, B_DIM * H_DIM, 256, 1.f);
  }

  // 9. task heads
  task_kernel<<<dim3(1), dim3(1024), 0, stream>>>(
      v_task, t_task, v_tw, v_tb, t_tw, t_tb, out_vta, out_tta);
}